// Round 5
// baseline (1795.420 us; speedup 1.0000x reference)
//
#include <hip/hip_runtime.h>
#include <hip/hip_bf16.h>
#include <float.h>

#define B_ 4
#define N_ 1024
#define DIM_ 1024
#define H_ 16
#define DH_ 64
#define NM_ 4
#define J_ 1028          // N_ + NM_
#define JP_ 514          // J_/2 pairs
#define JB_ 33           // ceil(J_/32) j-blocks
#define KR_ 1056         // padded kn rows (32-wide j-tiles always in-bounds)
#define IT_ 4            // i rows per attention block
#define JST 1032         // j stride in LDS (halves, even)
#define TOPK_ 64
#define QKSCALE 10.0f

typedef __attribute__((ext_vector_type(8))) short short8;
typedef __attribute__((ext_vector_type(4))) float f32x4;
typedef __attribute__((ext_vector_type(8))) unsigned short ushort8;
typedef __attribute__((ext_vector_type(4))) unsigned short ushort4v;
typedef __attribute__((ext_vector_type(4))) unsigned int u32x4;
typedef _Float16 half2v __attribute__((ext_vector_type(2)));

__device__ __forceinline__ unsigned short f2b(float f){
  union { float f; unsigned int i; } c; c.f = f;
  unsigned int r = c.i + 0x7FFFu + ((c.i >> 16) & 1u);   // RNE
  return (unsigned short)(r >> 16);
}
__device__ __forceinline__ unsigned short f2h(float f){
  return __builtin_bit_cast(unsigned short, (_Float16)f);
}
__device__ __forceinline__ float h2f(unsigned short u){
  return (float)__builtin_bit_cast(_Float16, u);
}
__device__ __forceinline__ float fdot2(unsigned int a, unsigned int b, float c){
  return __builtin_amdgcn_fdot2(__builtin_bit_cast(half2v, a),
                                __builtin_bit_cast(half2v, b), c, false);
}

// ---------------- f32 -> bf16 convert (grid-stride) ----------------
__global__ void k_cvt(const float* __restrict__ s, unsigned short* __restrict__ d, int n){
  int i = blockIdx.x * 256 + threadIdx.x;
  int st = gridDim.x * 256;
  for (; i < n; i += st) d[i] = f2b(s[i]);
}

// ---------------- memory-slot prep: normalize mem_k (f16), pack mem_v pairs ----------------
__global__ __launch_bounds__(256) void k_mem(const float* __restrict__ mk, const float* __restrict__ mv,
                                             unsigned short* __restrict__ kn, unsigned int* __restrict__ vp){
  int h = blockIdx.x * 4 + (threadIdx.x >> 6);   // 0..15
  int d = threadIdx.x & 63;
  unsigned short kh[4]; float vv[4];
  #pragma unroll
  for (int mm = 0; mm < 4; ++mm){
    float kv = mk[(h * 4 + mm) * 64 + d];
    float ss = kv * kv;
    #pragma unroll
    for (int off = 32; off; off >>= 1) ss += __shfl_xor(ss, off);
    kh[mm] = f2h(kv / fmaxf(sqrtf(ss), 1e-12f));
    vv[mm] = mv[(h * 4 + mm) * 64 + d];
  }
  unsigned int p01 = (unsigned int)f2h(vv[0]) | ((unsigned int)f2h(vv[1]) << 16);
  unsigned int p23 = (unsigned int)f2h(vv[2]) | ((unsigned int)f2h(vv[3]) << 16);
  for (int b = 0; b < B_; ++b){
    int bg = b * 16 + h;
    #pragma unroll
    for (int mm = 0; mm < 4; ++mm) kn[((size_t)bg * KR_ + mm) * 64 + d] = kh[mm];
    vp[((size_t)bg * JP_ + 0) * 64 + d] = p01;
    vp[((size_t)bg * JP_ + 1) * 64 + d] = p23;
  }
}

// ---- K re-tile: kn [bg][row][64d] f16 -> ktp [bg][jblk][dpq(8)][j%32][4] u32 pairs ----
// lane (fixed dpq) at column j reads 16 contiguous bytes: 4 d-pairs.
__global__ __launch_bounds__(256) void k_tr(const unsigned short* __restrict__ kn,
                                            unsigned int* __restrict__ ktp){
  __shared__ unsigned int tile[32][33];
  const int bg = blockIdx.y, jb = blockIdx.x, t = threadIdx.x;
  const unsigned int* src = (const unsigned int*)kn + (size_t)bg * KR_ * 32;
  {
    int j = t >> 3, c4 = (t & 7) * 4;
    int jr = jb * 32 + j;                       // < KR_ always
    u32x4 v = *(const u32x4*)(src + (size_t)jr * 32 + c4);
    tile[j][c4 + 0] = v[0]; tile[j][c4 + 1] = v[1];
    tile[j][c4 + 2] = v[2]; tile[j][c4 + 3] = v[3];
  }
  __syncthreads();
  {
    int dpq = t >> 5, jj = t & 31;
    u32x4 w;
    #pragma unroll
    for (int e = 0; e < 4; ++e) w[e] = tile[jj][dpq * 4 + e];
    *(u32x4*)(ktp + (((size_t)bg * JB_ + jb) * 8 + dpq) * 128 + jj * 4) = w;
  }
}

// ---------------- bf16 MFMA GEMM 4096x1024x1024, 128x128 tile, 4 waves ----------------
// MODE 0: v -> vp (f16 j-pair-packed u32 [bg][jp][64d])
// MODE 1: q -> qn f16 (l2norm*QKSCALE) ; MODE 2: k -> kn f16 (l2norm, KR_ stride)
// MODE 3: gate -> sigmoid(P+bg) f16 ; MODE 4: f32 out
template<int MODE>
__global__ __launch_bounds__(256) void k_gemm(const unsigned short* __restrict__ A,
                                              const unsigned short* __restrict__ W,
                                              void* __restrict__ outp,
                                              const float* __restrict__ bg)
{
  __shared__ unsigned short As[128][40];
  __shared__ unsigned short Bs[128][40];
  const int t = threadIdx.x;
  const int m0 = blockIdx.y * 128, n0 = blockIdx.x * 128;
  const int l = t & 63, w = t >> 6, wr = w >> 1, wc = w & 1;

  f32x4 acc[4][4];
  #pragma unroll
  for (int a = 0; a < 4; ++a)
    #pragma unroll
    for (int b2 = 0; b2 < 4; ++b2) acc[a][b2] = (f32x4){0.f, 0.f, 0.f, 0.f};

  for (int k0 = 0; k0 < 1024; k0 += 32){
    #pragma unroll
    for (int cc = 0; cc < 2; ++cc){
      int c = t + cc * 256;
      int row = c >> 2, colc = (c & 3) * 8;
      *(ushort8*)&As[row][colc] = *(const ushort8*)&A[(m0 + row) * 1024 + k0 + colc];
    }
    #pragma unroll
    for (int cc = 0; cc < 2; ++cc){
      int c = t + cc * 256;
      int kk = c >> 4, nc = (c & 15) * 8;
      ushort8 vb = *(const ushort8*)&W[(k0 + kk) * 1024 + n0 + nc];
      #pragma unroll
      for (int e = 0; e < 8; ++e) Bs[nc + e][kk] = vb[e];
    }
    __syncthreads();
    short8 af[4], bfr[4];
    #pragma unroll
    for (int mf = 0; mf < 4; ++mf) af[mf]  = *(const short8*)&As[wr * 64 + mf * 16 + (l & 15)][(l >> 4) * 8];
    #pragma unroll
    for (int nf = 0; nf < 4; ++nf) bfr[nf] = *(const short8*)&Bs[wc * 64 + nf * 16 + (l & 15)][(l >> 4) * 8];
    #pragma unroll
    for (int mf = 0; mf < 4; ++mf)
      #pragma unroll
      for (int nf = 0; nf < 4; ++nf)
        acc[mf][nf] = __builtin_amdgcn_mfma_f32_16x16x32_bf16(af[mf], bfr[nf], acc[mf][nf], 0, 0, 0);
    __syncthreads();
  }

  if constexpr (MODE == 0){
    #pragma unroll
    for (int mf = 0; mf < 4; ++mf){
      int row0 = m0 + wr * 64 + mf * 16 + (l >> 4) * 4;
      int bb = row0 >> 10, ii0 = row0 & 1023;
      int jp0 = (ii0 + NM_) >> 1;
      #pragma unroll
      for (int nf = 0; nf < 4; ++nf){
        int col = n0 + wc * 64 + nf * 16 + (l & 15);
        int h = col >> 6, d = col & 63;
        unsigned int p01 = (unsigned int)f2h(acc[mf][nf][0]) | ((unsigned int)f2h(acc[mf][nf][1]) << 16);
        unsigned int p23 = (unsigned int)f2h(acc[mf][nf][2]) | ((unsigned int)f2h(acc[mf][nf][3]) << 16);
        unsigned int* vpb = (unsigned int*)outp + ((size_t)(bb * 16 + h) * JP_ + jp0) * 64 + d;
        vpb[0]  = p01;
        vpb[64] = p23;
      }
    }
  } else {
    int hcol = (n0 + wc * 64) >> 6;
    #pragma unroll
    for (int mf = 0; mf < 4; ++mf){
      #pragma unroll
      for (int r = 0; r < 4; ++r){
        int row = m0 + wr * 64 + mf * 16 + (l >> 4) * 4 + r;
        float rn = 1.f;
        if (MODE == 1 || MODE == 2){
          float ss = 0.f;
          #pragma unroll
          for (int nf = 0; nf < 4; ++nf) ss += acc[mf][nf][r] * acc[mf][nf][r];
          #pragma unroll
          for (int off = 1; off < 16; off <<= 1) ss += __shfl_xor(ss, off);
          rn = 1.f / fmaxf(sqrtf(ss), 1e-12f);
          if (MODE == 1) rn *= QKSCALE;
        }
        #pragma unroll
        for (int nf = 0; nf < 4; ++nf){
          int col = n0 + wc * 64 + nf * 16 + (l & 15);
          float v = acc[mf][nf][r];
          if (MODE == 4){
            ((float*)outp)[row * 1024 + col] = v;
          } else if (MODE == 3){
            float g = v + bg[col];
            ((unsigned short*)outp)[row * 1024 + col] = f2h(1.f / (1.f + __expf(-g)));
          } else {
            int bb = row >> 10, ii = row & 1023;
            int d = nf * 16 + (l & 15);
            if (MODE == 1)
              ((unsigned short*)outp)[((bb * H_ + hcol) * N_ + ii) * DH_ + d] = f2h(v * rn);
            else
              ((unsigned short*)outp)[((size_t)(bb * H_ + hcol) * KR_ + NM_ + ii) * DH_ + d] = f2h(v * rn);
          }
        }
      }
    }
  }
}

// ---------------- fused attention: one workgroup per (b, 4-row i-tile) ----------------
// K and V each fetched ONCE per 4 query rows (4x L2-traffic reduction vs per-i blocks).
__global__ __launch_bounds__(1024) void k_attnT(
  const unsigned short* __restrict__ qn, const unsigned int* __restrict__ ktp,
  const unsigned int* __restrict__ vp, const float* __restrict__ wpre,
  const float* __restrict__ wpost, const float* __restrict__ hsc,
  const unsigned short* __restrict__ gate, unsigned short* __restrict__ aout)
{
  __shared__ unsigned short sd[16][IT_][JST];   // 132,096 B: raw -> mixed -> attn
  __shared__ float spre[256];
  __shared__ float spost[256];

  const int blk = blockIdx.x;
  const int b = blk & 3;
  const int it = 255 - (blk >> 2);     // big tiles first; per-CU 4-block sums balanced
  const int i0 = it * IT_;
  const int nAmax = i0 + IT_ + 4;      // j < i+5 for i = i0..i0+3
  const int t = threadIdx.x;

  if (t < 256){ spre[t] = wpre[t]; spost[t] = wpost[t]; }
  __syncthreads();

  // ---- phase A: raw dots for all 16 g, 4 i, thread = column j ----
  for (int j = t; j < nAmax; j += 1024){
    const int jblk = j >> 5, jj = j & 31;
    for (int g = 0; g < 16; ++g){
      const int bgi = b * 16 + g;
      const unsigned int* kb = ktp + (((size_t)bgi * JB_ + jblk) * 8) * 128 + jj * 4;
      u32x4 kk[8];
      #pragma unroll
      for (int dq = 0; dq < 8; ++dq) kk[dq] = *(const u32x4*)(kb + dq * 128);
      const unsigned int* qbase = (const unsigned int*)qn + ((size_t)bgi * 1024 + i0) * 32;
      #pragma unroll
      for (int i = 0; i < IT_; ++i){
        const unsigned int* qr = qbase + i * 32;    // wave-uniform -> s_load
        float s0 = 0.f, s1 = 0.f;
        #pragma unroll
        for (int dq = 0; dq < 8; ++dq){
          s0 = fdot2(qr[dq * 4 + 0], kk[dq][0], s0);
          s1 = fdot2(qr[dq * 4 + 1], kk[dq][1], s1);
          s0 = fdot2(qr[dq * 4 + 2], kk[dq][2], s0);
          s1 = fdot2(qr[dq * 4 + 3], kk[dq][3], s1);
        }
        sd[g][i][j] = f2h(s0 + s1);
      }
    }
  }
  __syncthreads();

  // ---- phase B: W_pre mix per column (in place, column-exclusive) ----
  for (int j = t; j < nAmax; j += 1024){
    #pragma unroll
    for (int i = 0; i < IT_; ++i){
      float a[16];
      #pragma unroll
      for (int g = 0; g < 16; ++g) a[g] = h2f(sd[g][i][j]);
      #pragma unroll
      for (int h = 0; h < 16; ++h){
        float m = 0.f;
        #pragma unroll
        for (int g = 0; g < 16; ++g) m += spre[h * 16 + g] * a[g];
        sd[h][i][j] = f2h(m);
      }
    }
  }
  __syncthreads();

  // ---- phase C: per-(h,i) top-64 threshold + softmax (one wave per row, 4 rows/wave) ----
  const int w = t >> 6, lane = t & 63;
  for (int r4 = 0; r4 < 4; ++r4){
    const int row = w + r4 * 16;           // 0..63
    const int h = row >> 2, ii = row & 3;
    const int nA = i0 + ii + 5;
    float v[17]; unsigned int key[17];
    #pragma unroll
    for (int r = 0; r < 17; ++r){
      int j = lane + 64 * r;
      if (j < nA){
        unsigned int u = sd[h][ii][j];
        key[r] = (u & 0x8000u) ? (~u & 0xFFFFu) : (u | 0x8000u);
        v[r] = h2f((unsigned short)u);
      } else { key[r] = 0u; v[r] = -3.0e38f; }
    }
    float mx = v[0];
    #pragma unroll
    for (int r = 1; r < 17; ++r) mx = fmaxf(mx, v[r]);
    #pragma unroll
    for (int off = 32; off; off >>= 1) mx = fmaxf(mx, __shfl_xor(mx, off));

    unsigned int T = 0u;
    if (nA > TOPK_){
      for (int bit = 15; bit >= 2; --bit){
        unsigned int Tc = T | (1u << bit);
        int c = 0;
        #pragma unroll
        for (int r = 0; r < 17; ++r)
          c += __popcll(__ballot(key[r] >= Tc));
        if (c >= TOPK_){
          T = Tc;
          if (c == TOPK_) break;
        }
      }
    }
    float s = 0.f;
    #pragma unroll
    for (int r = 0; r < 17; ++r){
      int j = lane + 64 * r;
      float e = (j < nA && key[r] >= T) ? __expf(v[r] - mx) : 0.f;
      v[r] = e; s += e;
    }
    #pragma unroll
    for (int off = 32; off; off >>= 1) s += __shfl_xor(s, off);
    float inv = 1.f / s;
    #pragma unroll
    for (int r = 0; r < 17; ++r){
      int j = lane + 64 * r;
      if (j < JST) sd[h][ii][j] = f2h(v[r] * inv);   // zeroes all garbage columns too
    }
  }
  __syncthreads();

  // ---- phase D: W_post mix per column (in place; zero cols stay zero) ----
  for (int j = t; j < nAmax; j += 1024){
    #pragma unroll
    for (int i = 0; i < IT_; ++i){
      float a[16];
      #pragma unroll
      for (int g = 0; g < 16; ++g) a[g] = h2f(sd[g][i][j]);
      #pragma unroll
      for (int h = 0; h < 16; ++h){
        float m = 0.f;
        #pragma unroll
        for (int g = 0; g < 16; ++g) m += spost[h * 16 + g] * a[g];
        sd[h][i][j] = f2h(m);
      }
    }
  }
  __syncthreads();

  // ---- phase E: PV via fdot2 over j-pairs; thread = (h, i, d-quad) ----
  // wave = one h, all 4 i, 16 dq -> each 16B v line serves 4 i's (coalesced + merged)
  {
    const int h = t >> 6;
    const int ii = (t >> 4) & 3;
    const int dq = t & 15;
    const int ig = i0 + ii;
    const int nA = ig + 5;
    const int npair = (nA + 1) >> 1;
    const int bgi = b * 16 + h;
    const unsigned int* vb = vp + (size_t)bgi * JP_ * 64 + dq * 4;
    const unsigned int* ap = (const unsigned int*)&sd[h][ii][0];
    f32x4 acc = (f32x4){0.f, 0.f, 0.f, 0.f};
    int jp = 0;
    for (; jp + 2 <= npair; jp += 2){
      unsigned int a0 = ap[jp], a1 = ap[jp + 1];
      u32x4 v0 = *(const u32x4*)(vb + (size_t)jp * 64);
      u32x4 v1 = *(const u32x4*)(vb + (size_t)(jp + 1) * 64);
      acc[0] = fdot2(v0[0], a0, acc[0]); acc[1] = fdot2(v0[1], a0, acc[1]);
      acc[2] = fdot2(v0[2], a0, acc[2]); acc[3] = fdot2(v0[3], a0, acc[3]);
      acc[0] = fdot2(v1[0], a1, acc[0]); acc[1] = fdot2(v1[1], a1, acc[1]);
      acc[2] = fdot2(v1[2], a1, acc[2]); acc[3] = fdot2(v1[3], a1, acc[3]);
    }
    for (; jp < npair; ++jp){
      unsigned int a0 = ap[jp];
      u32x4 v0 = *(const u32x4*)(vb + (size_t)jp * 64);
      acc[0] = fdot2(v0[0], a0, acc[0]); acc[1] = fdot2(v0[1], a0, acc[1]);
      acc[2] = fdot2(v0[2], a0, acc[2]); acc[3] = fdot2(v0[3], a0, acc[3]);
    }
    const float hs = hsc[h];
    const int row = (b << 10) | ig;
    const size_t obase = (size_t)row * 1024 + h * 64 + dq * 4;
    ushort4v gg = *(const ushort4v*)(gate + obase);
    #pragma unroll
    for (int e = 0; e < 4; ++e)
      aout[obase + e] = f2b(acc[e] * hs * h2f(gg[e]));
  }
}

// ---------------- host ----------------
extern "C" void kernel_launch(void* const* d_in, const int* in_sizes, int n_in,
                              void* d_out, int out_size, void* d_ws, size_t ws_size,
                              hipStream_t stream) {
  const float* x     = (const float*)d_in[0];
  const float* Wq    = (const float*)d_in[1];
  const float* Wk    = (const float*)d_in[2];
  const float* Wv    = (const float*)d_in[3];
  const float* Wpre  = (const float*)d_in[4];
  const float* Wpost = (const float*)d_in[5];
  const float* mk    = (const float*)d_in[6];
  const float* mv    = (const float*)d_in[7];
  const float* hsc   = (const float*)d_in[8];
  const float* Wg    = (const float*)d_in[9];
  const float* bg    = (const float*)d_in[10];
  const float* Wo    = (const float*)d_in[11];
  float* out = (float*)d_out;

  char* ws = (char*)d_ws;
  size_t off = 0;
  auto alloc = [&](size_t bytes) -> void* {
    void* p = ws + off; off += (bytes + 255) & ~(size_t)255; return p;
  };
  unsigned short* xb   = (unsigned short*)alloc((size_t)4096 * 1024 * 2);
  unsigned short* wqb  = (unsigned short*)alloc((size_t)1024 * 1024 * 2);
  unsigned short* wkb  = (unsigned short*)alloc((size_t)1024 * 1024 * 2);
  unsigned short* wvb  = (unsigned short*)alloc((size_t)1024 * 1024 * 2);
  unsigned short* wgb  = (unsigned short*)alloc((size_t)1024 * 1024 * 2);
  unsigned short* wob  = (unsigned short*)alloc((size_t)1024 * 1024 * 2);
  unsigned short* qn   = (unsigned short*)alloc((size_t)B_ * H_ * N_ * DH_ * 2);   // f16
  unsigned short* kn   = (unsigned short*)alloc((size_t)B_ * H_ * KR_ * DH_ * 2);  // f16 padded
  unsigned int*   vp   = (unsigned int*)alloc((size_t)B_ * H_ * JP_ * 64 * 4);
  unsigned short* gate = (unsigned short*)alloc((size_t)4096 * 1024 * 2);          // f16
  unsigned short* aout = (unsigned short*)alloc((size_t)4096 * 1024 * 2);          // bf16
  unsigned int*   ktp  = (unsigned int*)alloc((size_t)B_ * H_ * JB_ * 8 * 128 * 4);

  k_cvt<<<1024, 256, 0, stream>>>(x,  xb,  4096 * 1024);
  k_cvt<<<512,  256, 0, stream>>>(Wq, wqb, 1024 * 1024);
  k_cvt<<<512,  256, 0, stream>>>(Wk, wkb, 1024 * 1024);
  k_cvt<<<512,  256, 0, stream>>>(Wv, wvb, 1024 * 1024);
  k_cvt<<<512,  256, 0, stream>>>(Wg, wgb, 1024 * 1024);
  k_cvt<<<512,  256, 0, stream>>>(Wo, wob, 1024 * 1024);

  k_mem<<<4, 256, 0, stream>>>(mk, mv, kn, vp);

  dim3 gg(8, 32);
  k_gemm<0><<<gg, 256, 0, stream>>>(xb, wvb, vp,   nullptr);
  k_gemm<1><<<gg, 256, 0, stream>>>(xb, wqb, qn,   nullptr);
  k_gemm<2><<<gg, 256, 0, stream>>>(xb, wkb, kn,   nullptr);
  k_gemm<3><<<gg, 256, 0, stream>>>(xb, wgb, gate, bg);

  k_tr<<<dim3(JB_, B_ * H_), 256, 0, stream>>>(kn, ktp);

  k_attnT<<<1024, 1024, 0, stream>>>(qn, ktp, vp, Wpre, Wpost, hsc, gate, aout);

  k_gemm<4><<<gg, 256, 0, stream>>>(aout, wob, out, nullptr);
}

// Round 6
// 1613.523 us; speedup vs baseline: 1.1127x; 1.1127x over previous
//
#include <hip/hip_runtime.h>
#include <hip/hip_bf16.h>
#include <float.h>

#define B_ 4
#define N_ 1024
#define DIM_ 1024
#define H_ 16
#define DH_ 64
#define NM_ 4
#define J_ 1028          // N_ + NM_
#define JP_ 514          // J_/2 pairs
#define JB_ 33           // ceil(J_/32) j-blocks
#define KR_ 1056         // padded kn rows (32-wide j-tiles always in-bounds)
#define IT_ 4            // i rows per attention block
#define JST 1032         // j stride in LDS (halves, even)
#define TOPK_ 64
#define QKSCALE 10.0f

typedef __attribute__((ext_vector_type(8))) short short8;
typedef __attribute__((ext_vector_type(4))) float f32x4;
typedef __attribute__((ext_vector_type(8))) unsigned short ushort8;
typedef __attribute__((ext_vector_type(4))) unsigned short ushort4v;
typedef __attribute__((ext_vector_type(4))) unsigned int u32x4;
typedef _Float16 half2v __attribute__((ext_vector_type(2)));

__device__ __forceinline__ unsigned short f2b(float f){
  union { float f; unsigned int i; } c; c.f = f;
  unsigned int r = c.i + 0x7FFFu + ((c.i >> 16) & 1u);   // RNE
  return (unsigned short)(r >> 16);
}
__device__ __forceinline__ unsigned short f2h(float f){
  return __builtin_bit_cast(unsigned short, (_Float16)f);
}
__device__ __forceinline__ float h2f(unsigned short u){
  return (float)__builtin_bit_cast(_Float16, u);
}
__device__ __forceinline__ float fdot2(unsigned int a, unsigned int b, float c){
  return __builtin_amdgcn_fdot2(__builtin_bit_cast(half2v, a),
                                __builtin_bit_cast(half2v, b), c, false);
}
// order-preserving u16 key <-> f16 bits
__device__ __forceinline__ unsigned int h2key(unsigned int u){
  return (u & 0x8000u) ? (~u & 0xFFFFu) : (u | 0x8000u);
}
__device__ __forceinline__ float key2f(unsigned int k){
  unsigned int u = (k & 0x8000u) ? (k & 0x7FFFu) : (~k & 0xFFFFu);
  return h2f((unsigned short)u);
}

// ---------------- f32 -> bf16 convert (grid-stride) ----------------
__global__ void k_cvt(const float* __restrict__ s, unsigned short* __restrict__ d, int n){
  int i = blockIdx.x * 256 + threadIdx.x;
  int st = gridDim.x * 256;
  for (; i < n; i += st) d[i] = f2b(s[i]);
}

// ---------------- memory-slot prep: normalize mem_k (f16), pack mem_v pairs ----------------
__global__ __launch_bounds__(256) void k_mem(const float* __restrict__ mk, const float* __restrict__ mv,
                                             unsigned short* __restrict__ kn, unsigned int* __restrict__ vp){
  int h = blockIdx.x * 4 + (threadIdx.x >> 6);   // 0..15
  int d = threadIdx.x & 63;
  unsigned short kh[4]; float vv[4];
  #pragma unroll
  for (int mm = 0; mm < 4; ++mm){
    float kv = mk[(h * 4 + mm) * 64 + d];
    float ss = kv * kv;
    #pragma unroll
    for (int off = 32; off; off >>= 1) ss += __shfl_xor(ss, off);
    kh[mm] = f2h(kv / fmaxf(sqrtf(ss), 1e-12f));
    vv[mm] = mv[(h * 4 + mm) * 64 + d];
  }
  unsigned int p01 = (unsigned int)f2h(vv[0]) | ((unsigned int)f2h(vv[1]) << 16);
  unsigned int p23 = (unsigned int)f2h(vv[2]) | ((unsigned int)f2h(vv[3]) << 16);
  for (int b = 0; b < B_; ++b){
    int bg = b * 16 + h;
    #pragma unroll
    for (int mm = 0; mm < 4; ++mm) kn[((size_t)bg * KR_ + mm) * 64 + d] = kh[mm];
    vp[((size_t)bg * JP_ + 0) * 64 + d] = p01;
    vp[((size_t)bg * JP_ + 1) * 64 + d] = p23;
  }
}

// ---- K re-tile: kn [bg][row][64d] f16 -> ktp [bg][jblk][dpq(8)][j%32][4] u32 pairs ----
__global__ __launch_bounds__(256) void k_tr(const unsigned short* __restrict__ kn,
                                            unsigned int* __restrict__ ktp){
  __shared__ unsigned int tile[32][33];
  const int bg = blockIdx.y, jb = blockIdx.x, t = threadIdx.x;
  const unsigned int* src = (const unsigned int*)kn + (size_t)bg * KR_ * 32;
  {
    int j = t >> 3, c4 = (t & 7) * 4;
    int jr = jb * 32 + j;                       // < KR_ always
    u32x4 v = *(const u32x4*)(src + (size_t)jr * 32 + c4);
    tile[j][c4 + 0] = v[0]; tile[j][c4 + 1] = v[1];
    tile[j][c4 + 2] = v[2]; tile[j][c4 + 3] = v[3];
  }
  __syncthreads();
  {
    int dpq = t >> 5, jj = t & 31;
    u32x4 w;
    #pragma unroll
    for (int e = 0; e < 4; ++e) w[e] = tile[jj][dpq * 4 + e];
    *(u32x4*)(ktp + (((size_t)bg * JB_ + jb) * 8 + dpq) * 128 + jj * 4) = w;
  }
}

// ---------------- bf16 MFMA GEMM 4096x1024x1024, 128x128 tile, 4 waves ----------------
// MODE 0: v -> vp (f16 j-pair-packed u32 [bg][jp][64d])
// MODE 1: q -> qn f16 (l2norm*QKSCALE) ; MODE 2: k -> kn f16 (l2norm, KR_ stride)
// MODE 3: gate -> sigmoid(P+bg) f16 ; MODE 4: f32 out
template<int MODE>
__global__ __launch_bounds__(256) void k_gemm(const unsigned short* __restrict__ A,
                                              const unsigned short* __restrict__ W,
                                              void* __restrict__ outp,
                                              const float* __restrict__ bg)
{
  __shared__ unsigned short As[128][40];
  __shared__ unsigned short Bs[128][40];
  const int t = threadIdx.x;
  const int m0 = blockIdx.y * 128, n0 = blockIdx.x * 128;
  const int l = t & 63, w = t >> 6, wr = w >> 1, wc = w & 1;

  f32x4 acc[4][4];
  #pragma unroll
  for (int a = 0; a < 4; ++a)
    #pragma unroll
    for (int b2 = 0; b2 < 4; ++b2) acc[a][b2] = (f32x4){0.f, 0.f, 0.f, 0.f};

  for (int k0 = 0; k0 < 1024; k0 += 32){
    #pragma unroll
    for (int cc = 0; cc < 2; ++cc){
      int c = t + cc * 256;
      int row = c >> 2, colc = (c & 3) * 8;
      *(ushort8*)&As[row][colc] = *(const ushort8*)&A[(m0 + row) * 1024 + k0 + colc];
    }
    #pragma unroll
    for (int cc = 0; cc < 2; ++cc){
      int c = t + cc * 256;
      int kk = c >> 4, nc = (c & 15) * 8;
      ushort8 vb = *(const ushort8*)&W[(k0 + kk) * 1024 + n0 + nc];
      #pragma unroll
      for (int e = 0; e < 8; ++e) Bs[nc + e][kk] = vb[e];
    }
    __syncthreads();
    short8 af[4], bfr[4];
    #pragma unroll
    for (int mf = 0; mf < 4; ++mf) af[mf]  = *(const short8*)&As[wr * 64 + mf * 16 + (l & 15)][(l >> 4) * 8];
    #pragma unroll
    for (int nf = 0; nf < 4; ++nf) bfr[nf] = *(const short8*)&Bs[wc * 64 + nf * 16 + (l & 15)][(l >> 4) * 8];
    #pragma unroll
    for (int mf = 0; mf < 4; ++mf)
      #pragma unroll
      for (int nf = 0; nf < 4; ++nf)
        acc[mf][nf] = __builtin_amdgcn_mfma_f32_16x16x32_bf16(af[mf], bfr[nf], acc[mf][nf], 0, 0, 0);
    __syncthreads();
  }

  if constexpr (MODE == 0){
    #pragma unroll
    for (int mf = 0; mf < 4; ++mf){
      int row0 = m0 + wr * 64 + mf * 16 + (l >> 4) * 4;
      int bb = row0 >> 10, ii0 = row0 & 1023;
      int jp0 = (ii0 + NM_) >> 1;
      #pragma unroll
      for (int nf = 0; nf < 4; ++nf){
        int col = n0 + wc * 64 + nf * 16 + (l & 15);
        int h = col >> 6, d = col & 63;
        unsigned int p01 = (unsigned int)f2h(acc[mf][nf][0]) | ((unsigned int)f2h(acc[mf][nf][1]) << 16);
        unsigned int p23 = (unsigned int)f2h(acc[mf][nf][2]) | ((unsigned int)f2h(acc[mf][nf][3]) << 16);
        unsigned int* vpb = (unsigned int*)outp + ((size_t)(bb * 16 + h) * JP_ + jp0) * 64 + d;
        vpb[0]  = p01;
        vpb[64] = p23;
      }
    }
  } else {
    int hcol = (n0 + wc * 64) >> 6;
    #pragma unroll
    for (int mf = 0; mf < 4; ++mf){
      #pragma unroll
      for (int r = 0; r < 4; ++r){
        int row = m0 + wr * 64 + mf * 16 + (l >> 4) * 4 + r;
        float rn = 1.f;
        if (MODE == 1 || MODE == 2){
          float ss = 0.f;
          #pragma unroll
          for (int nf = 0; nf < 4; ++nf) ss += acc[mf][nf][r] * acc[mf][nf][r];
          #pragma unroll
          for (int off = 1; off < 16; off <<= 1) ss += __shfl_xor(ss, off);
          rn = 1.f / fmaxf(sqrtf(ss), 1e-12f);
          if (MODE == 1) rn *= QKSCALE;
        }
        #pragma unroll
        for (int nf = 0; nf < 4; ++nf){
          int col = n0 + wc * 64 + nf * 16 + (l & 15);
          float v = acc[mf][nf][r];
          if (MODE == 4){
            ((float*)outp)[row * 1024 + col] = v;
          } else if (MODE == 3){
            float g = v + bg[col];
            ((unsigned short*)outp)[row * 1024 + col] = f2h(1.f / (1.f + __expf(-g)));
          } else {
            int bb = row >> 10, ii = row & 1023;
            int d = nf * 16 + (l & 15);
            if (MODE == 1)
              ((unsigned short*)outp)[((bb * H_ + hcol) * N_ + ii) * DH_ + d] = f2h(v * rn);
            else
              ((unsigned short*)outp)[((size_t)(bb * H_ + hcol) * KR_ + NM_ + ii) * DH_ + d] = f2h(v * rn);
          }
        }
      }
    }
  }
}

// ---------------- fused attention: one workgroup (512 thr) per (b, 4-row i-tile) ----------------
// K and V each fetched once per 4 query rows. No per-thread arrays beyond key[17] (reg-lean).
__global__ __launch_bounds__(512) void k_attnT(
  const unsigned short* __restrict__ qn, const unsigned int* __restrict__ ktp,
  const unsigned int* __restrict__ vp, const float* __restrict__ wpre,
  const float* __restrict__ wpost, const float* __restrict__ hsc,
  const unsigned short* __restrict__ gate, unsigned short* __restrict__ aout)
{
  __shared__ unsigned short sd[16][IT_][JST];   // 132,096 B: raw -> mixed -> attn
  __shared__ float spre[256];
  __shared__ float spost[256];

  const int blk = blockIdx.x;
  const int b = blk & 3;
  const int it = 255 - (blk >> 2);     // big tiles first
  const int i0 = it * IT_;
  const int nAmax = i0 + IT_ + 4;      // j < i+5 for i = i0..i0+3
  const int t = threadIdx.x;

  if (t < 256){ spre[t] = wpre[t]; spost[t] = wpost[t]; }
  __syncthreads();

  // ---- phase A: raw dots for all 16 g, 4 i; thread = column j ----
  for (int j = t; j < nAmax; j += 512){
    const int jblk = j >> 5, jj = j & 31;
    for (int g = 0; g < 16; ++g){
      const int bgi = b * 16 + g;
      const unsigned int* kb = ktp + (((size_t)bgi * JB_ + jblk) * 8) * 128 + jj * 4;
      u32x4 kk[8];
      #pragma unroll
      for (int dq = 0; dq < 8; ++dq) kk[dq] = *(const u32x4*)(kb + dq * 128);
      const unsigned int* qbase = (const unsigned int*)qn + ((size_t)bgi * 1024 + i0) * 32;
      #pragma unroll
      for (int i = 0; i < IT_; ++i){
        const unsigned int* qr = qbase + i * 32;    // wave-uniform -> s_load
        float s0 = 0.f, s1 = 0.f;
        #pragma unroll
        for (int dq = 0; dq < 8; ++dq){
          s0 = fdot2(qr[dq * 4 + 0], kk[dq][0], s0);
          s1 = fdot2(qr[dq * 4 + 1], kk[dq][1], s1);
          s0 = fdot2(qr[dq * 4 + 2], kk[dq][2], s0);
          s1 = fdot2(qr[dq * 4 + 3], kk[dq][3], s1);
        }
        sd[g][i][j] = f2h(s0 + s1);
      }
    }
  }
  __syncthreads();

  // ---- phase B: W_pre mix per column (in place, column-exclusive) ----
  for (int j = t; j < nAmax; j += 512){
    #pragma unroll
    for (int i = 0; i < IT_; ++i){
      float a[16];
      #pragma unroll
      for (int g = 0; g < 16; ++g) a[g] = h2f(sd[g][i][j]);
      #pragma unroll
      for (int h = 0; h < 16; ++h){
        float m = 0.f;
        #pragma unroll
        for (int g = 0; g < 16; ++g) m += spre[h * 16 + g] * a[g];
        sd[h][i][j] = f2h(m);
      }
    }
  }
  __syncthreads();

  // ---- phase C: per-(h,i) top-64 + softmax; wave per row, keys only (no float array) ----
  const int w = t >> 6, lane = t & 63;
  #pragma unroll
  for (int r8 = 0; r8 < 8; ++r8){
    const int row = w * 8 + r8;            // 0..63
    const int h = row >> 2, ii = row & 3;
    const int nA = i0 + ii + 5;
    unsigned int key[17];
    #pragma unroll
    for (int r = 0; r < 17; ++r){
      int j = lane + 64 * r;
      key[r] = (j < nA) ? h2key((unsigned int)sd[h][ii][j]) : 0u;
    }
    unsigned int kmx = key[0];
    #pragma unroll
    for (int r = 1; r < 17; ++r) kmx = max(kmx, key[r]);
    #pragma unroll
    for (int off = 32; off; off >>= 1) kmx = max(kmx, (unsigned int)__shfl_xor((int)kmx, off));
    const float mx = key2f(kmx);

    unsigned int T = 0u;
    if (nA > TOPK_){
      for (int bit = 15; bit >= 2; --bit){
        unsigned int Tc = T | (1u << bit);
        int c = 0;
        #pragma unroll
        for (int r = 0; r < 17; ++r)
          c += __popcll(__ballot(key[r] >= Tc));
        if (c >= TOPK_){
          T = Tc;
          if (c == TOPK_) break;
        }
      }
    }
    float s = 0.f;
    float ev[17];
    #pragma unroll
    for (int r = 0; r < 17; ++r){
      int j = lane + 64 * r;
      float e = (j < nA && key[r] >= T) ? __expf(key2f(key[r]) - mx) : 0.f;
      ev[r] = e; s += e;
    }
    #pragma unroll
    for (int off = 32; off; off >>= 1) s += __shfl_xor(s, off);
    float inv = 1.f / s;
    #pragma unroll
    for (int r = 0; r < 17; ++r){
      int j = lane + 64 * r;
      if (j < JST) sd[h][ii][j] = f2h(ev[r] * inv);   // zeroes padding columns too
    }
  }
  __syncthreads();

  // ---- phase D: W_post mix per column (in place; zero cols stay zero) ----
  for (int j = t; j < nAmax; j += 512){
    #pragma unroll
    for (int i = 0; i < IT_; ++i){
      float a[16];
      #pragma unroll
      for (int g = 0; g < 16; ++g) a[g] = h2f(sd[g][i][j]);
      #pragma unroll
      for (int h = 0; h < 16; ++h){
        float m = 0.f;
        #pragma unroll
        for (int g = 0; g < 16; ++g) m += spost[h * 16 + g] * a[g];
        sd[h][i][j] = f2h(m);
      }
    }
  }
  __syncthreads();

  // ---- phase E: PV via fdot2 over j-pairs; thread = (h, ii, d-octet) ----
  // 4 ii's in a wave share each 256B V line (L2-coalesced; V fetched once per 4 rows).
  {
    const int h = t >> 5;
    const int ii = (t >> 3) & 3;
    const int dq = t & 7;                 // 8 d's per thread
    const int ig = i0 + ii;
    const int nA = ig + 5;
    const int npair = (nA + 1) >> 1;
    const int bgi = b * 16 + h;
    const unsigned int* vb = vp + (size_t)bgi * JP_ * 64 + dq * 8;
    const unsigned int* ap = (const unsigned int*)&sd[h][ii][0];
    float acc[8] = {0.f,0.f,0.f,0.f,0.f,0.f,0.f,0.f};
    for (int jp = 0; jp < npair; ++jp){
      unsigned int a0 = ap[jp];
      u32x4 v0 = *(const u32x4*)(vb + (size_t)jp * 64);
      u32x4 v1 = *(const u32x4*)(vb + (size_t)jp * 64 + 4);
      acc[0] = fdot2(v0[0], a0, acc[0]); acc[1] = fdot2(v0[1], a0, acc[1]);
      acc[2] = fdot2(v0[2], a0, acc[2]); acc[3] = fdot2(v0[3], a0, acc[3]);
      acc[4] = fdot2(v1[0], a0, acc[4]); acc[5] = fdot2(v1[1], a0, acc[5]);
      acc[6] = fdot2(v1[2], a0, acc[6]); acc[7] = fdot2(v1[3], a0, acc[7]);
    }
    const float hs = hsc[h];
    const int row = (b << 10) | ig;
    const size_t obase = (size_t)row * 1024 + h * 64 + dq * 8;
    ushort8 gg = *(const ushort8*)(gate + obase);
    ushort8 ov;
    #pragma unroll
    for (int e = 0; e < 8; ++e) ov[e] = f2b(acc[e] * hs * h2f(gg[e]));
    *(ushort8*)(aout + obase) = ov;
  }
}

// ---------------- host ----------------
extern "C" void kernel_launch(void* const* d_in, const int* in_sizes, int n_in,
                              void* d_out, int out_size, void* d_ws, size_t ws_size,
                              hipStream_t stream) {
  const float* x     = (const float*)d_in[0];
  const float* Wq    = (const float*)d_in[1];
  const float* Wk    = (const float*)d_in[2];
  const float* Wv    = (const float*)d_in[3];
  const float* Wpre  = (const float*)d_in[4];
  const float* Wpost = (const float*)d_in[5];
  const float* mk    = (const float*)d_in[6];
  const float* mv    = (const float*)d_in[7];
  const float* hsc   = (const float*)d_in[8];
  const float* Wg    = (const float*)d_in[9];
  const float* bg    = (const float*)d_in[10];
  const float* Wo    = (const float*)d_in[11];
  float* out = (float*)d_out;

  char* ws = (char*)d_ws;
  size_t off = 0;
  auto alloc = [&](size_t bytes) -> void* {
    void* p = ws + off; off += (bytes + 255) & ~(size_t)255; return p;
  };
  unsigned short* xb   = (unsigned short*)alloc((size_t)4096 * 1024 * 2);
  unsigned short* wqb  = (unsigned short*)alloc((size_t)1024 * 1024 * 2);
  unsigned short* wkb  = (unsigned short*)alloc((size_t)1024 * 1024 * 2);
  unsigned short* wvb  = (unsigned short*)alloc((size_t)1024 * 1024 * 2);
  unsigned short* wgb  = (unsigned short*)alloc((size_t)1024 * 1024 * 2);
  unsigned short* wob  = (unsigned short*)alloc((size_t)1024 * 1024 * 2);
  unsigned short* qn   = (unsigned short*)alloc((size_t)B_ * H_ * N_ * DH_ * 2);   // f16
  unsigned short* kn   = (unsigned short*)alloc((size_t)B_ * H_ * KR_ * DH_ * 2);  // f16 padded
  unsigned int*   vp   = (unsigned int*)alloc((size_t)B_ * H_ * JP_ * 64 * 4);
  unsigned short* gate = (unsigned short*)alloc((size_t)4096 * 1024 * 2);          // f16
  unsigned short* aout = (unsigned short*)alloc((size_t)4096 * 1024 * 2);          // bf16
  unsigned int*   ktp  = (unsigned int*)alloc((size_t)B_ * H_ * JB_ * 8 * 128 * 4);

  k_cvt<<<1024, 256, 0, stream>>>(x,  xb,  4096 * 1024);
  k_cvt<<<512,  256, 0, stream>>>(Wq, wqb, 1024 * 1024);
  k_cvt<<<512,  256, 0, stream>>>(Wk, wkb, 1024 * 1024);
  k_cvt<<<512,  256, 0, stream>>>(Wv, wvb, 1024 * 1024);
  k_cvt<<<512,  256, 0, stream>>>(Wg, wgb, 1024 * 1024);
  k_cvt<<<512,  256, 0, stream>>>(Wo, wob, 1024 * 1024);

  k_mem<<<4, 256, 0, stream>>>(mk, mv, kn, vp);

  dim3 gg(8, 32);
  k_gemm<0><<<gg, 256, 0, stream>>>(xb, wvb, vp,   nullptr);
  k_gemm<1><<<gg, 256, 0, stream>>>(xb, wqb, qn,   nullptr);
  k_gemm<2><<<gg, 256, 0, stream>>>(xb, wkb, kn,   nullptr);
  k_gemm<3><<<gg, 256, 0, stream>>>(xb, wgb, gate, bg);

  k_tr<<<dim3(JB_, B_ * H_), 256, 0, stream>>>(kn, ktp);

  k_attnT<<<1024, 512, 0, stream>>>(qn, ktp, vp, Wpre, Wpost, hsc, gate, aout);

  k_gemm<4><<<gg, 256, 0, stream>>>(aout, wob, out, nullptr);
}

// Round 7
// 782.880 us; speedup vs baseline: 2.2934x; 2.0610x over previous
//
#include <hip/hip_runtime.h>
#include <hip/hip_bf16.h>
#include <float.h>

#define B_ 4
#define N_ 1024
#define H_ 16
#define DH_ 64
#define NM_ 4
#define J_ 1028          // N_ + NM_
#define KR_ 1056         // padded kn/vc rows
#define JST2 1056        // sd row length (halves), 16B-aligned rows
#define NJ_ 66           // 16-wide j-tiles covering 1056
#define TOPK_ 64
#define QKSCALE 10.0f

typedef __attribute__((ext_vector_type(8))) short short8;
typedef __attribute__((ext_vector_type(4))) float f32x4;
typedef __attribute__((ext_vector_type(8))) unsigned short ushort8;
typedef __attribute__((ext_vector_type(4))) unsigned int u32x4;
typedef _Float16 half8 __attribute__((ext_vector_type(8)));

__device__ __forceinline__ unsigned short f2b(float f){
  union { float f; unsigned int i; } c; c.f = f;
  unsigned int r = c.i + 0x7FFFu + ((c.i >> 16) & 1u);   // RNE
  return (unsigned short)(r >> 16);
}
__device__ __forceinline__ unsigned short f2h(float f){
  return __builtin_bit_cast(unsigned short, (_Float16)f);
}
__device__ __forceinline__ float h2f(unsigned short u){
  return (float)__builtin_bit_cast(_Float16, u);
}
// order-preserving u16 key <-> f16 bits
__device__ __forceinline__ unsigned int h2key(unsigned int u){
  return (u & 0x8000u) ? (~u & 0xFFFFu) : (u | 0x8000u);
}
__device__ __forceinline__ float key2f(unsigned int k){
  unsigned int u = (k & 0x8000u) ? (k & 0x7FFFu) : (~k & 0xFFFFu);
  return h2f((unsigned short)u);
}

// ---------------- f32 -> bf16 convert (grid-stride) ----------------
__global__ void k_cvt(const float* __restrict__ s, unsigned short* __restrict__ d, int n){
  int i = blockIdx.x * 256 + threadIdx.x;
  int st = gridDim.x * 256;
  for (; i < n; i += st) d[i] = f2b(s[i]);
}

// ---------------- memory-slot prep: normalize mem_k (f16), copy mem_v (f16) ----------------
__global__ __launch_bounds__(256) void k_mem(const float* __restrict__ mk, const float* __restrict__ mv,
                                             unsigned short* __restrict__ kn, unsigned short* __restrict__ vc){
  int h = blockIdx.x * 4 + (threadIdx.x >> 6);   // 0..15
  int d = threadIdx.x & 63;
  unsigned short kh[4], vh[4];
  #pragma unroll
  for (int mm = 0; mm < 4; ++mm){
    float kv = mk[(h * 4 + mm) * 64 + d];
    float ss = kv * kv;
    #pragma unroll
    for (int off = 32; off; off >>= 1) ss += __shfl_xor(ss, off);
    kh[mm] = f2h(kv / fmaxf(sqrtf(ss), 1e-12f));
    vh[mm] = f2h(mv[(h * 4 + mm) * 64 + d]);
  }
  for (int b = 0; b < B_; ++b){
    int bg = b * 16 + h;
    #pragma unroll
    for (int mm = 0; mm < 4; ++mm){
      kn[((size_t)bg * KR_ + mm) * 64 + d] = kh[mm];
      vc[((size_t)bg * KR_ + mm) * 64 + d] = vh[mm];
    }
  }
}

// ---------------- V transpose: vc [bg][j][64] f16 -> vt [bg][64][1056] f16 ----------------
__global__ __launch_bounds__(256) void k_trv(const unsigned short* __restrict__ vc,
                                             unsigned short* __restrict__ vt){
  __shared__ unsigned short tile[32][72];
  const int jb = blockIdx.x;           // 0..32
  const int bg = blockIdx.y;           // 0..63
  const int t = threadIdx.x;
  {
    int r = t >> 3, d8 = (t & 7) * 8;
    ushort8 v = *(const ushort8*)(vc + ((size_t)bg * KR_ + jb * 32 + r) * 64 + d8);
    #pragma unroll
    for (int e = 0; e < 8; ++e) tile[r][d8 + e] = v[e];
  }
  __syncthreads();
  {
    int d = t >> 2, j8 = (t & 3) * 8;
    ushort8 w;
    #pragma unroll
    for (int e = 0; e < 8; ++e) w[e] = tile[j8 + e][d];
    *(ushort8*)(vt + ((size_t)bg * 64 + d) * 1056 + jb * 32 + j8) = w;
  }
}

// ---------------- bf16 MFMA GEMM 4096x1024x1024, 128x128 tile, 4 waves ----------------
// MODE 0: v -> vc f16 [bg][KR_][64] ; MODE 1: q -> qn f16 (l2norm*QKSCALE)
// MODE 2: k -> kn f16 (l2norm, KR_) ; MODE 3: gate -> sigmoid f16 ; MODE 4: f32 out
template<int MODE>
__global__ __launch_bounds__(256) void k_gemm(const unsigned short* __restrict__ A,
                                              const unsigned short* __restrict__ W,
                                              void* __restrict__ outp,
                                              const float* __restrict__ bg)
{
  __shared__ unsigned short As[128][40];
  __shared__ unsigned short Bs[128][40];
  const int t = threadIdx.x;
  const int m0 = blockIdx.y * 128, n0 = blockIdx.x * 128;
  const int l = t & 63, w = t >> 6, wr = w >> 1, wc = w & 1;

  f32x4 acc[4][4];
  #pragma unroll
  for (int a = 0; a < 4; ++a)
    #pragma unroll
    for (int b2 = 0; b2 < 4; ++b2) acc[a][b2] = (f32x4){0.f, 0.f, 0.f, 0.f};

  for (int k0 = 0; k0 < 1024; k0 += 32){
    #pragma unroll
    for (int cc = 0; cc < 2; ++cc){
      int c = t + cc * 256;
      int row = c >> 2, colc = (c & 3) * 8;
      *(ushort8*)&As[row][colc] = *(const ushort8*)&A[(m0 + row) * 1024 + k0 + colc];
    }
    #pragma unroll
    for (int cc = 0; cc < 2; ++cc){
      int c = t + cc * 256;
      int kk = c >> 4, nc = (c & 15) * 8;
      ushort8 vb = *(const ushort8*)&W[(k0 + kk) * 1024 + n0 + nc];
      #pragma unroll
      for (int e = 0; e < 8; ++e) Bs[nc + e][kk] = vb[e];
    }
    __syncthreads();
    short8 af[4], bfr[4];
    #pragma unroll
    for (int mf = 0; mf < 4; ++mf) af[mf]  = *(const short8*)&As[wr * 64 + mf * 16 + (l & 15)][(l >> 4) * 8];
    #pragma unroll
    for (int nf = 0; nf < 4; ++nf) bfr[nf] = *(const short8*)&Bs[wc * 64 + nf * 16 + (l & 15)][(l >> 4) * 8];
    #pragma unroll
    for (int mf = 0; mf < 4; ++mf)
      #pragma unroll
      for (int nf = 0; nf < 4; ++nf)
        acc[mf][nf] = __builtin_amdgcn_mfma_f32_16x16x32_bf16(af[mf], bfr[nf], acc[mf][nf], 0, 0, 0);
    __syncthreads();
  }

  int hcol = (n0 + wc * 64) >> 6;
  #pragma unroll
  for (int mf = 0; mf < 4; ++mf){
    #pragma unroll
    for (int r = 0; r < 4; ++r){
      int row = m0 + wr * 64 + mf * 16 + (l >> 4) * 4 + r;
      float rn = 1.f;
      if (MODE == 1 || MODE == 2){
        float ss = 0.f;
        #pragma unroll
        for (int nf = 0; nf < 4; ++nf) ss += acc[mf][nf][r] * acc[mf][nf][r];
        #pragma unroll
        for (int off = 1; off < 16; off <<= 1) ss += __shfl_xor(ss, off);
        rn = 1.f / fmaxf(sqrtf(ss), 1e-12f);
        if (MODE == 1) rn *= QKSCALE;
      }
      #pragma unroll
      for (int nf = 0; nf < 4; ++nf){
        int col = n0 + wc * 64 + nf * 16 + (l & 15);
        float v = acc[mf][nf][r];
        if (MODE == 4){
          ((float*)outp)[row * 1024 + col] = v;
        } else if (MODE == 3){
          float g = v + bg[col];
          ((unsigned short*)outp)[row * 1024 + col] = f2h(1.f / (1.f + __expf(-g)));
        } else {
          int bb = row >> 10, ii = row & 1023;
          int d = nf * 16 + (l & 15);
          if (MODE == 1)
            ((unsigned short*)outp)[((bb * H_ + hcol) * N_ + ii) * DH_ + d] = f2h(v * rn);
          else // MODE 0 (rn=1) and MODE 2: padded KR_ layout
            ((unsigned short*)outp)[((size_t)(bb * H_ + hcol) * KR_ + NM_ + ii) * DH_ + d] = f2h(v * rn);
        }
      }
    }
  }
}

// ---------------- fused attention, all-MFMA: one workgroup (512 thr) per (b, 4-i tile) ----------------
__global__ __launch_bounds__(512) void k_attnM(
  const unsigned short* __restrict__ qn, const unsigned short* __restrict__ kn,
  const unsigned short* __restrict__ vt, const float* __restrict__ wpre,
  const float* __restrict__ wpost, const float* __restrict__ hsc,
  const unsigned short* __restrict__ gate, unsigned short* __restrict__ aout)
{
  __shared__ unsigned short sd[16 * 4 * JST2];   // [head][i][j] f16: raw -> premixed -> e -> a_post
  __shared__ unsigned short wpre16[16 * 32];     // Wpre f16, zero-padded K=32
  __shared__ unsigned short w2[4 * 16 * 32];     // Wpost * (1/s), per ii, zero-padded
  __shared__ float sinv[64];                     // 1/rowsum per (g*4+ii)

  const int blk = blockIdx.x;
  const int b = blk & 3;
  const int it = 255 - (blk >> 2);               // big tiles first
  const int i0 = it * 4;
  const int nAmax = i0 + 8;                      // max per-row nA (= i0+3+5)
  const int nJtA = (nAmax + 15) >> 4;
  const int t = threadIdx.x;
  const int w = t >> 6, l = t & 63;
  const int l15 = l & 15, l4 = l >> 4;

  if (t < 256){
    int h = t >> 4, g = t & 15;
    wpre16[h * 32 + g]      = f2h(wpre[h * 16 + g]);
    wpre16[h * 32 + 16 + g] = 0;
  }
  __syncthreads();

  // ---- phase A: raw dots via MFMA; F1 = K rows (j), F2 = q rows (i) ----
  for (int g = 0; g < 16; ++g){
    const int bg = b * 16 + g;
    const unsigned short* qb = qn + ((size_t)bg * N_ + i0 + (l15 & 3)) * 64 + l4 * 8;
    half8 qf0 = *(const half8*)(qb);
    half8 qf1 = *(const half8*)(qb + 32);
    const unsigned short* kb0 = kn + (size_t)bg * KR_ * 64 + (size_t)l15 * 64 + l4 * 8;
    for (int jt = w; jt < nJtA; jt += 8){
      const unsigned short* kb = kb0 + (size_t)jt * 16 * 64;
      half8 kf0 = *(const half8*)(kb);
      half8 kf1 = *(const half8*)(kb + 32);
      f32x4 acc = (f32x4){0.f, 0.f, 0.f, 0.f};
      acc = __builtin_amdgcn_mfma_f32_16x16x32_f16(kf0, qf0, acc, 0, 0, 0);
      acc = __builtin_amdgcn_mfma_f32_16x16x32_f16(kf1, qf1, acc, 0, 0, 0);
      if (l15 < 4){
        // D: row (j-off) = l4*4+r, col (i) = l15
        unsigned int p0 = (unsigned int)f2h(acc[0]) | ((unsigned int)f2h(acc[1]) << 16);
        unsigned int p1 = (unsigned int)f2h(acc[2]) | ((unsigned int)f2h(acc[3]) << 16);
        unsigned int* dst = (unsigned int*)&sd[(g * 4 + l15) * JST2 + jt * 16 + l4 * 4];
        dst[0] = p0; dst[1] = p1;
      }
    }
  }
  __syncthreads();

  // ---- phase B: W_pre premix via MFMA, in-place per (ii, jt16) patch ----
  {
    half8 wa = *(const half8*)&wpre16[l15 * 32 + l4 * 8];   // F1 row = h, k = g (0 for k>=16)
    const int ntask = 4 * nJtA;
    for (int task = w; task < ntask; task += 8){
      const int ii = task & 3, jt = task >> 2;
      unsigned int fb[4] = {0u, 0u, 0u, 0u};
      if (l4 < 2){
        const unsigned short* src = &sd[((l4 * 8) * 4 + ii) * JST2 + jt * 16 + l15];
        #pragma unroll
        for (int e = 0; e < 8; e += 2){
          unsigned int lo = src[(size_t)(e)     * 4 * JST2];
          unsigned int hi = src[(size_t)(e + 1) * 4 * JST2];
          fb[e >> 1] = (lo & 0xFFFFu) | (hi << 16);
        }
      }
      f32x4 acc = (f32x4){0.f, 0.f, 0.f, 0.f};
      acc = __builtin_amdgcn_mfma_f32_16x16x32_f16(wa, __builtin_bit_cast(half8, *(u32x4*)fb), acc, 0, 0, 0);
      #pragma unroll
      for (int r = 0; r < 4; ++r)
        sd[((l4 * 4 + r) * 4 + ii) * JST2 + jt * 16 + l15] = f2h(acc[r]);
    }
  }
  __syncthreads();

  // ---- phase C: per-row top-64 threshold + softmax (unnormalized e; 1/s saved) ----
  for (int rr = 0; rr < 8; ++rr){
    const int row = w * 8 + rr;            // 0..63
    const int g = row >> 2, ii = row & 3;
    const int nA = i0 + ii + 5;
    unsigned short* rowp = &sd[(g * 4 + ii) * JST2];
    unsigned int kw[9];
    #pragma unroll
    for (int grp = 0; grp < 9; ++grp){
      int j = grp * 128 + l * 2;
      unsigned int u = (j < JST2) ? *(const unsigned int*)(rowp + j) : 0u;
      unsigned int klo = h2key(u & 0xFFFFu);
      unsigned int khi = h2key(u >> 16);
      if (j     >= nA) klo = 0u;
      if (j + 1 >= nA) khi = 0u;
      kw[grp] = klo | (khi << 16);
    }
    unsigned int kmx = 0u;
    #pragma unroll
    for (int grp = 0; grp < 9; ++grp){
      unsigned int m2 = max(kw[grp] >> 16, kw[grp] & 0xFFFFu);
      kmx = max(kmx, m2);
    }
    #pragma unroll
    for (int off = 32; off; off >>= 1) kmx = max(kmx, (unsigned int)__shfl_xor((int)kmx, off));
    const float mx = key2f(kmx);

    unsigned int T = 0u;
    if (nA > TOPK_){
      for (int bit = 15; bit >= 2; --bit){
        unsigned int Tc = T | (1u << bit);
        int c = 0;
        #pragma unroll
        for (int grp = 0; grp < 9; ++grp){
          c += __popcll(__ballot((kw[grp] & 0xFFFFu) >= Tc));
          c += __popcll(__ballot((kw[grp] >> 16) >= Tc));
        }
        if (c >= TOPK_){
          T = Tc;
          if (c == TOPK_) break;
        }
      }
    }
    if (T == 0u) T = 1u;     // excludes masked (key 0), keeps everything valid

    float s = 0.f;
    #pragma unroll
    for (int grp = 0; grp < 9; ++grp){
      unsigned int klo = kw[grp] & 0xFFFFu, khi = kw[grp] >> 16;
      float elo = (klo >= T) ? __expf(key2f(klo) - mx) : 0.f;
      float ehi = (khi >= T) ? __expf(key2f(khi) - mx) : 0.f;
      s += elo + ehi;
      int j = grp * 128 + l * 2;
      if (j < JST2)
        *(unsigned int*)(rowp + j) = (unsigned int)f2h(elo) | ((unsigned int)f2h(ehi) << 16);
    }
    #pragma unroll
    for (int off = 32; off; off >>= 1) s += __shfl_xor(s, off);
    if (l == 0) sinv[row] = 1.f / s;
  }
  __syncthreads();

  // ---- fold row normalization into W_post: w2[ii][h][g] = Wpost[h][g] * sinv[g][ii] ----
  if (t < 256){
    int h = t >> 4, g = t & 15;
    float wp = wpost[h * 16 + g];
    #pragma unroll
    for (int ii = 0; ii < 4; ++ii){
      w2[(ii * 16 + h) * 32 + g]      = f2h(wp * sinv[g * 4 + ii]);
      w2[(ii * 16 + h) * 32 + 16 + g] = 0;
    }
  }
  __syncthreads();

  // ---- phase D: postmix via MFMA (covers ALL 66 tiles; zero cols stay zero) ----
  {
    const int ntask = 4 * NJ_;
    for (int task = w; task < ntask; task += 8){
      const int ii = task & 3, jt = task >> 2;
      half8 wa = *(const half8*)&w2[(ii * 16 + l15) * 32 + l4 * 8];
      unsigned int fb[4] = {0u, 0u, 0u, 0u};
      if (l4 < 2){
        const unsigned short* src = &sd[((l4 * 8) * 4 + ii) * JST2 + jt * 16 + l15];
        #pragma unroll
        for (int e = 0; e < 8; e += 2){
          unsigned int lo = src[(size_t)(e)     * 4 * JST2];
          unsigned int hi = src[(size_t)(e + 1) * 4 * JST2];
          fb[e >> 1] = (lo & 0xFFFFu) | (hi << 16);
        }
      }
      f32x4 acc = (f32x4){0.f, 0.f, 0.f, 0.f};
      acc = __builtin_amdgcn_mfma_f32_16x16x32_f16(wa, __builtin_bit_cast(half8, *(u32x4*)fb), acc, 0, 0, 0);
      #pragma unroll
      for (int r = 0; r < 4; ++r)
        sd[((l4 * 4 + r) * 4 + ii) * JST2 + jt * 16 + l15] = f2h(acc[r]);
    }
  }
  __syncthreads();

  // ---- phase E: PV via MFMA over j; F1 = a_post rows (i), F2 = V^T rows (d) ----
  for (int task = w; task < 64; task += 8){
    const int h = task >> 2, dc = task & 3;
    const int bg = b * 16 + h;
    const unsigned short* vrow = vt + ((size_t)bg * 64 + dc * 16 + l15) * 1056 + l4 * 8;
    const unsigned short* arow = &sd[(h * 4 + (l15 & 3)) * JST2 + l4 * 8];
    f32x4 acc = (f32x4){0.f, 0.f, 0.f, 0.f};
    for (int jt = 0; jt < 33; ++jt){
      half8 af = *(const half8*)(arow + jt * 32);
      half8 vf = *(const half8*)(vrow + jt * 32);
      acc = __builtin_amdgcn_mfma_f32_16x16x32_f16(af, vf, acc, 0, 0, 0);
    }
    if (l4 == 0){
      const float hs = hsc[h];
      #pragma unroll
      for (int r = 0; r < 4; ++r){
        const int irow = (b << 10) | (i0 + r);
        const size_t o = (size_t)irow * 1024 + h * 64 + dc * 16 + l15;
        aout[o] = f2b(acc[r] * hs * h2f(gate[o]));
      }
    }
  }
}

// ---------------- host ----------------
extern "C" void kernel_launch(void* const* d_in, const int* in_sizes, int n_in,
                              void* d_out, int out_size, void* d_ws, size_t ws_size,
                              hipStream_t stream) {
  const float* x     = (const float*)d_in[0];
  const float* Wq    = (const float*)d_in[1];
  const float* Wk    = (const float*)d_in[2];
  const float* Wv    = (const float*)d_in[3];
  const float* Wpre  = (const float*)d_in[4];
  const float* Wpost = (const float*)d_in[5];
  const float* mk    = (const float*)d_in[6];
  const float* mv    = (const float*)d_in[7];
  const float* hsc   = (const float*)d_in[8];
  const float* Wg    = (const float*)d_in[9];
  const float* bg    = (const float*)d_in[10];
  const float* Wo    = (const float*)d_in[11];
  float* out = (float*)d_out;

  char* ws = (char*)d_ws;
  size_t off = 0;
  auto alloc = [&](size_t bytes) -> void* {
    void* p = ws + off; off += (bytes + 255) & ~(size_t)255; return p;
  };
  unsigned short* xb   = (unsigned short*)alloc((size_t)4096 * 1024 * 2);
  unsigned short* wqb  = (unsigned short*)alloc((size_t)1024 * 1024 * 2);
  unsigned short* wkb  = (unsigned short*)alloc((size_t)1024 * 1024 * 2);
  unsigned short* wvb  = (unsigned short*)alloc((size_t)1024 * 1024 * 2);
  unsigned short* wgb  = (unsigned short*)alloc((size_t)1024 * 1024 * 2);
  unsigned short* wob  = (unsigned short*)alloc((size_t)1024 * 1024 * 2);
  unsigned short* qn   = (unsigned short*)alloc((size_t)B_ * H_ * N_ * DH_ * 2);   // f16
  unsigned short* kn   = (unsigned short*)alloc((size_t)B_ * H_ * KR_ * DH_ * 2);  // f16 padded
  unsigned short* vc   = (unsigned short*)alloc((size_t)B_ * H_ * KR_ * DH_ * 2);  // f16 padded
  unsigned short* vt   = (unsigned short*)alloc((size_t)B_ * H_ * DH_ * 1056 * 2); // f16 V^T
  unsigned short* gate = (unsigned short*)alloc((size_t)4096 * 1024 * 2);          // f16
  unsigned short* aout = (unsigned short*)alloc((size_t)4096 * 1024 * 2);          // bf16

  k_cvt<<<1024, 256, 0, stream>>>(x,  xb,  4096 * 1024);
  k_cvt<<<512,  256, 0, stream>>>(Wq, wqb, 1024 * 1024);
  k_cvt<<<512,  256, 0, stream>>>(Wk, wkb, 1024 * 1024);
  k_cvt<<<512,  256, 0, stream>>>(Wv, wvb, 1024 * 1024);
  k_cvt<<<512,  256, 0, stream>>>(Wg, wgb, 1024 * 1024);
  k_cvt<<<512,  256, 0, stream>>>(Wo, wob, 1024 * 1024);

  k_mem<<<4, 256, 0, stream>>>(mk, mv, kn, vc);

  dim3 gg(8, 32);
  k_gemm<0><<<gg, 256, 0, stream>>>(xb, wvb, vc,   nullptr);
  k_gemm<1><<<gg, 256, 0, stream>>>(xb, wqb, qn,   nullptr);
  k_gemm<2><<<gg, 256, 0, stream>>>(xb, wkb, kn,   nullptr);
  k_gemm<3><<<gg, 256, 0, stream>>>(xb, wgb, gate, bg);

  k_trv<<<dim3(33, B_ * H_), 256, 0, stream>>>(vc, vt);

  k_attnM<<<1024, 512, 0, stream>>>(qn, kn, vt, Wpre, Wpost, hsc, gate, aout);

  k_gemm<4><<<gg, 256, 0, stream>>>(aout, wob, out, nullptr);
}

// Round 8
// 678.723 us; speedup vs baseline: 2.6453x; 1.1535x over previous
//
#include <hip/hip_runtime.h>
#include <hip/hip_bf16.h>
#include <float.h>

#define B_ 4
#define N_ 1024
#define H_ 16
#define DH_ 64
#define NM_ 4
#define J_ 1028          // N_ + NM_
#define KR_ 1056         // padded kn/vc rows
#define JST2 1064        // sd row stride (halves): mult of 8, 4-row stride != 0 mod 32 banks
#define TOPK_ 64
#define QKSCALE 10.0f

typedef __attribute__((ext_vector_type(8))) short short8;
typedef __attribute__((ext_vector_type(4))) float f32x4;
typedef __attribute__((ext_vector_type(8))) unsigned short ushort8;
typedef __attribute__((ext_vector_type(4))) unsigned int u32x4;
typedef _Float16 half8 __attribute__((ext_vector_type(8)));

__device__ __forceinline__ unsigned short f2b(float f){
  union { float f; unsigned int i; } c; c.f = f;
  unsigned int r = c.i + 0x7FFFu + ((c.i >> 16) & 1u);   // RNE
  return (unsigned short)(r >> 16);
}
__device__ __forceinline__ unsigned short f2h(float f){
  return __builtin_bit_cast(unsigned short, (_Float16)f);
}
__device__ __forceinline__ float h2f(unsigned short u){
  return (float)__builtin_bit_cast(_Float16, u);
}
// order-preserving u16 key <-> f16 bits
__device__ __forceinline__ unsigned int h2key(unsigned int u){
  return (u & 0x8000u) ? (~u & 0xFFFFu) : (u | 0x8000u);
}
__device__ __forceinline__ float key2f(unsigned int k){
  unsigned int u = (k & 0x8000u) ? (k & 0x7FFFu) : (~k & 0xFFFFu);
  return h2f((unsigned short)u);
}

// ---------------- f32 -> bf16 convert (grid-stride) ----------------
__global__ void k_cvt(const float* __restrict__ s, unsigned short* __restrict__ d, int n){
  int i = blockIdx.x * 256 + threadIdx.x;
  int st = gridDim.x * 256;
  for (; i < n; i += st) d[i] = f2b(s[i]);
}

// ---------------- memory-slot prep: normalize mem_k (f16), copy mem_v (f16) ----------------
__global__ __launch_bounds__(256) void k_mem(const float* __restrict__ mk, const float* __restrict__ mv,
                                             unsigned short* __restrict__ kn, unsigned short* __restrict__ vc){
  int h = blockIdx.x * 4 + (threadIdx.x >> 6);   // 0..15
  int d = threadIdx.x & 63;
  unsigned short kh[4], vh[4];
  #pragma unroll
  for (int mm = 0; mm < 4; ++mm){
    float kv = mk[(h * 4 + mm) * 64 + d];
    float ss = kv * kv;
    #pragma unroll
    for (int off = 32; off; off >>= 1) ss += __shfl_xor(ss, off);
    kh[mm] = f2h(kv / fmaxf(sqrtf(ss), 1e-12f));
    vh[mm] = f2h(mv[(h * 4 + mm) * 64 + d]);
  }
  for (int b = 0; b < B_; ++b){
    int bg = b * 16 + h;
    #pragma unroll
    for (int mm = 0; mm < 4; ++mm){
      kn[((size_t)bg * KR_ + mm) * 64 + d] = kh[mm];
      vc[((size_t)bg * KR_ + mm) * 64 + d] = vh[mm];
    }
  }
}

// ---------------- V transpose: vc [bg][j][64] f16 -> vt [bg][64][1056] f16 ----------------
__global__ __launch_bounds__(256) void k_trv(const unsigned short* __restrict__ vc,
                                             unsigned short* __restrict__ vt){
  __shared__ unsigned short tile[32][72];
  const int jb = blockIdx.x;           // 0..32
  const int bg = blockIdx.y;           // 0..63
  const int t = threadIdx.x;
  {
    int r = t >> 3, d8 = (t & 7) * 8;
    ushort8 v = *(const ushort8*)(vc + ((size_t)bg * KR_ + jb * 32 + r) * 64 + d8);
    #pragma unroll
    for (int e = 0; e < 8; ++e) tile[r][d8 + e] = v[e];
  }
  __syncthreads();
  {
    int d = t >> 2, j8 = (t & 3) * 8;
    ushort8 w;
    #pragma unroll
    for (int e = 0; e < 8; ++e) w[e] = tile[j8 + e][d];
    *(ushort8*)(vt + ((size_t)bg * 64 + d) * 1056 + jb * 32 + j8) = w;
  }
}

// ---------------- bf16 MFMA GEMM 4096x1024x1024, 128x128 tile, 4 waves ----------------
// MODE 0: v -> vc f16 [bg][KR_][64] ; MODE 1: q -> qn f16 (l2norm*QKSCALE)
// MODE 2: k -> kn f16 (l2norm, KR_) ; MODE 3: gate -> sigmoid f16 ; MODE 4: f32 out
template<int MODE>
__global__ __launch_bounds__(256) void k_gemm(const unsigned short* __restrict__ A,
                                              const unsigned short* __restrict__ W,
                                              void* __restrict__ outp,
                                              const float* __restrict__ bg)
{
  __shared__ unsigned short As[128][40];
  __shared__ unsigned short Bs[128][40];
  const int t = threadIdx.x;
  const int m0 = blockIdx.y * 128, n0 = blockIdx.x * 128;
  const int l = t & 63, w = t >> 6, wr = w >> 1, wc = w & 1;

  f32x4 acc[4][4];
  #pragma unroll
  for (int a = 0; a < 4; ++a)
    #pragma unroll
    for (int b2 = 0; b2 < 4; ++b2) acc[a][b2] = (f32x4){0.f, 0.f, 0.f, 0.f};

  for (int k0 = 0; k0 < 1024; k0 += 32){
    #pragma unroll
    for (int cc = 0; cc < 2; ++cc){
      int c = t + cc * 256;
      int row = c >> 2, colc = (c & 3) * 8;
      *(ushort8*)&As[row][colc] = *(const ushort8*)&A[(m0 + row) * 1024 + k0 + colc];
    }
    #pragma unroll
    for (int cc = 0; cc < 2; ++cc){
      int c = t + cc * 256;
      int kk = c >> 4, nc = (c & 15) * 8;
      ushort8 vb = *(const ushort8*)&W[(k0 + kk) * 1024 + n0 + nc];
      #pragma unroll
      for (int e = 0; e < 8; ++e) Bs[nc + e][kk] = vb[e];
    }
    __syncthreads();
    short8 af[4], bfr[4];
    #pragma unroll
    for (int mf = 0; mf < 4; ++mf) af[mf]  = *(const short8*)&As[wr * 64 + mf * 16 + (l & 15)][(l >> 4) * 8];
    #pragma unroll
    for (int nf = 0; nf < 4; ++nf) bfr[nf] = *(const short8*)&Bs[wc * 64 + nf * 16 + (l & 15)][(l >> 4) * 8];
    #pragma unroll
    for (int mf = 0; mf < 4; ++mf)
      #pragma unroll
      for (int nf = 0; nf < 4; ++nf)
        acc[mf][nf] = __builtin_amdgcn_mfma_f32_16x16x32_bf16(af[mf], bfr[nf], acc[mf][nf], 0, 0, 0);
    __syncthreads();
  }

  int hcol = (n0 + wc * 64) >> 6;
  #pragma unroll
  for (int mf = 0; mf < 4; ++mf){
    #pragma unroll
    for (int r = 0; r < 4; ++r){
      int row = m0 + wr * 64 + mf * 16 + (l >> 4) * 4 + r;
      float rn = 1.f;
      if (MODE == 1 || MODE == 2){
        float ss = 0.f;
        #pragma unroll
        for (int nf = 0; nf < 4; ++nf) ss += acc[mf][nf][r] * acc[mf][nf][r];
        #pragma unroll
        for (int off = 1; off < 16; off <<= 1) ss += __shfl_xor(ss, off);
        rn = 1.f / fmaxf(sqrtf(ss), 1e-12f);
        if (MODE == 1) rn *= QKSCALE;
      }
      #pragma unroll
      for (int nf = 0; nf < 4; ++nf){
        int col = n0 + wc * 64 + nf * 16 + (l & 15);
        float v = acc[mf][nf][r];
        if (MODE == 4){
          ((float*)outp)[row * 1024 + col] = v;
        } else if (MODE == 3){
          float g = v + bg[col];
          ((unsigned short*)outp)[row * 1024 + col] = f2h(1.f / (1.f + __expf(-g)));
        } else {
          int bb = row >> 10, ii = row & 1023;
          int d = nf * 16 + (l & 15);
          if (MODE == 1)
            ((unsigned short*)outp)[((bb * H_ + hcol) * N_ + ii) * DH_ + d] = f2h(v * rn);
          else // MODE 0 (rn=1) and MODE 2: padded KR_ layout
            ((unsigned short*)outp)[((size_t)(bb * H_ + hcol) * KR_ + NM_ + ii) * DH_ + d] = f2h(v * rn);
        }
      }
    }
  }
}

// ---------------- fused attention, all-MFMA: 1024 thr (16 waves) per (b, 4-i tile) ----------------
// XCD-swizzled: blk%8 -> XCD (round-robin); b fixed per XCD-pair so K/V (~4MB) stays L2-resident.
__global__ __launch_bounds__(1024) void k_attnM(
  const unsigned short* __restrict__ qn, const unsigned short* __restrict__ kn,
  const unsigned short* __restrict__ vt, const float* __restrict__ wpre,
  const float* __restrict__ wpost, const float* __restrict__ hsc,
  const unsigned short* __restrict__ gate, unsigned short* __restrict__ aout)
{
  __shared__ unsigned short sd[16 * 4 * JST2];   // [head][i][j] f16: raw -> premixed -> e -> a_post
  __shared__ unsigned short wpre16[16 * 32];     // Wpre f16, zero-padded K=32
  __shared__ unsigned short w2[4 * 16 * 32];     // Wpost * (1/s), per ii, zero-padded
  __shared__ float sinv[64];                     // 1/rowsum per (g*4+ii)

  const int blk = blockIdx.x;
  const int b = (blk >> 1) & 3;                  // fixed per XCD pair (blk%8 -> XCD)
  const int idx = ((blk >> 3) << 1) | (blk & 1); // 0..255, ascending within XCD
  const int it = 255 - idx;                      // big tiles first
  const int i0 = it * 4;
  const int nAmax = i0 + 8;                      // max per-row nA (= i0+3+5)
  const int nJtA = (nAmax + 15) >> 4;            // 16-tiles for dots/premix
  const int nJtE = (nAmax + 31) >> 5;            // 32-tiles for PV
  const int nJtD = nJtE * 2;                     // 16-tiles for postmix (covers E's reach)
  const int t = threadIdx.x;
  const int w = t >> 6, l = t & 63;
  const int l15 = l & 15, l4 = l >> 4;

  if (t < 256){
    int h = t >> 4, g = t & 15;
    wpre16[h * 32 + g]      = f2h(wpre[h * 16 + g]);
    wpre16[h * 32 + 16 + g] = 0;
  }
  __syncthreads();

  // ---- phase A: raw dots via MFMA; F1 = K rows (j), F2 = q rows (i) ----
  for (int g = 0; g < 16; ++g){
    const int bg = b * 16 + g;
    const unsigned short* qb = qn + ((size_t)bg * N_ + i0 + (l15 & 3)) * 64 + l4 * 8;
    half8 qf0 = *(const half8*)(qb);
    half8 qf1 = *(const half8*)(qb + 32);
    const unsigned short* kb0 = kn + (size_t)bg * KR_ * 64 + (size_t)l15 * 64 + l4 * 8;
    for (int jt = w; jt < nJtA; jt += 16){
      const unsigned short* kb = kb0 + (size_t)jt * 16 * 64;
      half8 kf0 = *(const half8*)(kb);
      half8 kf1 = *(const half8*)(kb + 32);
      f32x4 acc = (f32x4){0.f, 0.f, 0.f, 0.f};
      acc = __builtin_amdgcn_mfma_f32_16x16x32_f16(kf0, qf0, acc, 0, 0, 0);
      acc = __builtin_amdgcn_mfma_f32_16x16x32_f16(kf1, qf1, acc, 0, 0, 0);
      if (l15 < 4){
        // D: row (j-off) = l4*4+r, col (i) = l15
        unsigned int p0 = (unsigned int)f2h(acc[0]) | ((unsigned int)f2h(acc[1]) << 16);
        unsigned int p1 = (unsigned int)f2h(acc[2]) | ((unsigned int)f2h(acc[3]) << 16);
        unsigned int* dst = (unsigned int*)&sd[(g * 4 + l15) * JST2 + jt * 16 + l4 * 4];
        dst[0] = p0; dst[1] = p1;
      }
    }
  }
  __syncthreads();

  // ---- phase B: W_pre premix via MFMA, in-place per (ii, jt16) patch ----
  {
    half8 wa = *(const half8*)&wpre16[l15 * 32 + l4 * 8];   // F1 row = h, k = g (0 for k>=16)
    const int ntask = 4 * nJtA;
    for (int task = w; task < ntask; task += 16){
      const int ii = task & 3, jt = task >> 2;
      unsigned int fb[4] = {0u, 0u, 0u, 0u};
      if (l4 < 2){
        const unsigned short* src = &sd[((l4 * 8) * 4 + ii) * JST2 + jt * 16 + l15];
        #pragma unroll
        for (int e = 0; e < 8; e += 2){
          unsigned int lo = src[(size_t)(e)     * 4 * JST2];
          unsigned int hi = src[(size_t)(e + 1) * 4 * JST2];
          fb[e >> 1] = (lo & 0xFFFFu) | (hi << 16);
        }
      }
      f32x4 acc = (f32x4){0.f, 0.f, 0.f, 0.f};
      acc = __builtin_amdgcn_mfma_f32_16x16x32_f16(wa, __builtin_bit_cast(half8, *(u32x4*)fb), acc, 0, 0, 0);
      #pragma unroll
      for (int r = 0; r < 4; ++r)
        sd[((l4 * 4 + r) * 4 + ii) * JST2 + jt * 16 + l15] = f2h(acc[r]);
    }
  }
  __syncthreads();

  // ---- phase C: per-row top-64 threshold + softmax (unnormalized e; 1/s saved) ----
  for (int rr = 0; rr < 4; ++rr){
    const int row = w * 4 + rr;            // 0..63
    const int g = row >> 2, ii = row & 3;
    const int nA = i0 + ii + 5;
    unsigned short* rowp = &sd[(g * 4 + ii) * JST2];
    unsigned int kw[9];
    #pragma unroll
    for (int grp = 0; grp < 9; ++grp){
      int j = grp * 128 + l * 2;
      unsigned int u = (j < JST2) ? *(const unsigned int*)(rowp + j) : 0u;
      unsigned int klo = h2key(u & 0xFFFFu);
      unsigned int khi = h2key(u >> 16);
      if (j     >= nA) klo = 0u;
      if (j + 1 >= nA) khi = 0u;
      kw[grp] = klo | (khi << 16);
    }
    unsigned int kmx = 0u;
    #pragma unroll
    for (int grp = 0; grp < 9; ++grp){
      unsigned int m2 = max(kw[grp] >> 16, kw[grp] & 0xFFFFu);
      kmx = max(kmx, m2);
    }
    #pragma unroll
    for (int off = 32; off; off >>= 1) kmx = max(kmx, (unsigned int)__shfl_xor((int)kmx, off));
    const float mx = key2f(kmx);

    unsigned int T = 0u;
    if (nA > TOPK_){
      for (int bit = 15; bit >= 2; --bit){
        unsigned int Tc = T | (1u << bit);
        int c = 0;
        #pragma unroll
        for (int grp = 0; grp < 9; ++grp){
          c += __popcll(__ballot((kw[grp] & 0xFFFFu) >= Tc));
          c += __popcll(__ballot((kw[grp] >> 16) >= Tc));
        }
        if (c >= TOPK_){
          T = Tc;
          if (c == TOPK_) break;
        }
      }
    }
    if (T == 0u) T = 1u;     // excludes masked (key 0), keeps everything valid

    float s = 0.f;
    #pragma unroll
    for (int grp = 0; grp < 9; ++grp){
      unsigned int klo = kw[grp] & 0xFFFFu, khi = kw[grp] >> 16;
      float elo = (klo >= T) ? __expf(key2f(klo) - mx) : 0.f;
      float ehi = (khi >= T) ? __expf(key2f(khi) - mx) : 0.f;
      s += elo + ehi;
      int j = grp * 128 + l * 2;
      if (j < JST2)
        *(unsigned int*)(rowp + j) = (unsigned int)f2h(elo) | ((unsigned int)f2h(ehi) << 16);
    }
    #pragma unroll
    for (int off = 32; off; off >>= 1) s += __shfl_xor(s, off);
    if (l == 0) sinv[row] = 1.f / s;
  }
  __syncthreads();

  // ---- fold row normalization into W_post: w2[ii][h][g] = Wpost[h][g] * sinv[g][ii] ----
  if (t < 256){
    int h = t >> 4, g = t & 15;
    float wp = wpost[h * 16 + g];
    #pragma unroll
    for (int ii = 0; ii < 4; ++ii){
      w2[(ii * 16 + h) * 32 + g]      = f2h(wp * sinv[g * 4 + ii]);
      w2[(ii * 16 + h) * 32 + 16 + g] = 0;
    }
  }
  __syncthreads();

  // ---- phase D: postmix via MFMA (causal-trimmed; zero cols stay zero) ----
  {
    const int ntask = 4 * nJtD;
    for (int task = w; task < ntask; task += 16){
      const int ii = task & 3, jt = task >> 2;
      half8 wa = *(const half8*)&w2[(ii * 16 + l15) * 32 + l4 * 8];
      unsigned int fb[4] = {0u, 0u, 0u, 0u};
      if (l4 < 2){
        const unsigned short* src = &sd[((l4 * 8) * 4 + ii) * JST2 + jt * 16 + l15];
        #pragma unroll
        for (int e = 0; e < 8; e += 2){
          unsigned int lo = src[(size_t)(e)     * 4 * JST2];
          unsigned int hi = src[(size_t)(e + 1) * 4 * JST2];
          fb[e >> 1] = (lo & 0xFFFFu) | (hi << 16);
        }
      }
      f32x4 acc = (f32x4){0.f, 0.f, 0.f, 0.f};
      acc = __builtin_amdgcn_mfma_f32_16x16x32_f16(wa, __builtin_bit_cast(half8, *(u32x4*)fb), acc, 0, 0, 0);
      #pragma unroll
      for (int r = 0; r < 4; ++r)
        sd[((l4 * 4 + r) * 4 + ii) * JST2 + jt * 16 + l15] = f2h(acc[r]);
    }
  }
  __syncthreads();

  // ---- phase E: PV via MFMA over j (causal-trimmed); F1 = a_post rows (i), F2 = V^T rows (d) ----
  for (int task = w; task < 64; task += 16){
    const int h = task >> 2, dc = task & 3;
    const int bg = b * 16 + h;
    const unsigned short* vrow = vt + ((size_t)bg * 64 + dc * 16 + l15) * 1056 + l4 * 8;
    const unsigned short* arow = &sd[(h * 4 + (l15 & 3)) * JST2 + l4 * 8];
    f32x4 acc = (f32x4){0.f, 0.f, 0.f, 0.f};
    for (int jt = 0; jt < nJtE; ++jt){
      half8 af = *(const half8*)(arow + jt * 32);
      half8 vf = *(const half8*)(vrow + jt * 32);
      acc = __builtin_amdgcn_mfma_f32_16x16x32_f16(af, vf, acc, 0, 0, 0);
    }
    if (l4 == 0){
      const float hs = hsc[h];
      #pragma unroll
      for (int r = 0; r < 4; ++r){
        const int irow = (b << 10) | (i0 + r);
        const size_t o = (size_t)irow * 1024 + h * 64 + dc * 16 + l15;
        aout[o] = f2b(acc[r] * hs * h2f(gate[o]));
      }
    }
  }
}

// ---------------- host ----------------
extern "C" void kernel_launch(void* const* d_in, const int* in_sizes, int n_in,
                              void* d_out, int out_size, void* d_ws, size_t ws_size,
                              hipStream_t stream) {
  const float* x     = (const float*)d_in[0];
  const float* Wq    = (const float*)d_in[1];
  const float* Wk    = (const float*)d_in[2];
  const float* Wv    = (const float*)d_in[3];
  const float* Wpre  = (const float*)d_in[4];
  const float* Wpost = (const float*)d_in[5];
  const float* mk    = (const float*)d_in[6];
  const float* mv    = (const float*)d_in[7];
  const float* hsc   = (const float*)d_in[8];
  const float* Wg    = (const float*)d_in[9];
  const float* bg    = (const float*)d_in[10];
  const float* Wo    = (const float*)d_in[11];
  float* out = (float*)d_out;

  char* ws = (char*)d_ws;
  size_t off = 0;
  auto alloc = [&](size_t bytes) -> void* {
    void* p = ws + off; off += (bytes + 255) & ~(size_t)255; return p;
  };
  unsigned short* xb   = (unsigned short*)alloc((size_t)4096 * 1024 * 2);
  unsigned short* wqb  = (unsigned short*)alloc((size_t)1024 * 1024 * 2);
  unsigned short* wkb  = (unsigned short*)alloc((size_t)1024 * 1024 * 2);
  unsigned short* wvb  = (unsigned short*)alloc((size_t)1024 * 1024 * 2);
  unsigned short* wgb  = (unsigned short*)alloc((size_t)1024 * 1024 * 2);
  unsigned short* wob  = (unsigned short*)alloc((size_t)1024 * 1024 * 2);
  unsigned short* qn   = (unsigned short*)alloc((size_t)B_ * H_ * N_ * DH_ * 2);   // f16
  unsigned short* kn   = (unsigned short*)alloc((size_t)B_ * H_ * KR_ * DH_ * 2);  // f16 padded
  unsigned short* vc   = (unsigned short*)alloc((size_t)B_ * H_ * KR_ * DH_ * 2);  // f16 padded
  unsigned short* vt   = (unsigned short*)alloc((size_t)B_ * H_ * DH_ * 1056 * 2); // f16 V^T
  unsigned short* gate = (unsigned short*)alloc((size_t)4096 * 1024 * 2);          // f16
  unsigned short* aout = (unsigned short*)alloc((size_t)4096 * 1024 * 2);          // bf16

  k_cvt<<<1024, 256, 0, stream>>>(x,  xb,  4096 * 1024);
  k_cvt<<<512,  256, 0, stream>>>(Wq, wqb, 1024 * 1024);
  k_cvt<<<512,  256, 0, stream>>>(Wk, wkb, 1024 * 1024);
  k_cvt<<<512,  256, 0, stream>>>(Wv, wvb, 1024 * 1024);
  k_cvt<<<512,  256, 0, stream>>>(Wg, wgb, 1024 * 1024);
  k_cvt<<<512,  256, 0, stream>>>(Wo, wob, 1024 * 1024);

  k_mem<<<4, 256, 0, stream>>>(mk, mv, kn, vc);

  dim3 gg(8, 32);
  k_gemm<0><<<gg, 256, 0, stream>>>(xb, wvb, vc,   nullptr);
  k_gemm<1><<<gg, 256, 0, stream>>>(xb, wqb, qn,   nullptr);
  k_gemm<2><<<gg, 256, 0, stream>>>(xb, wkb, kn,   nullptr);
  k_gemm<3><<<gg, 256, 0, stream>>>(xb, wgb, gate, bg);

  k_trv<<<dim3(33, B_ * H_), 256, 0, stream>>>(vc, vt);

  k_attnM<<<1024, 1024, 0, stream>>>(qn, kn, vt, Wpre, Wpost, hsc, gate, aout);

  k_gemm<4><<<gg, 256, 0, stream>>>(aout, wob, out, nullptr);
}